// Round 9
// baseline (291.618 us; speedup 1.0000x reference)
//
#include <hip/hip_runtime.h>
#include <hip/hip_bf16.h>

typedef unsigned short u16;
typedef int i32x4 __attribute__((ext_vector_type(4)));
typedef signed char s8;

#define NB_RED 256

// ---------------- min/max reduction (4 tensors) ----------------
__global__ void k_minmax_partial(const float* __restrict__ x, const float* __restrict__ h,
                                 const float* __restrict__ wi, const float* __restrict__ wh,
                                 float* __restrict__ partials) {
    int t = blockIdx.y;
    const float* p = (t == 0) ? x : (t == 1) ? h : (t == 2) ? wi : wh;
    int n4 = ((t < 2) ? (8192 * 1024) : (4096 * 1024)) >> 2;
    float mn = 3.4e38f, mx = -3.4e38f;
    const float4* p4 = (const float4*)p;
    for (int i = blockIdx.x * blockDim.x + threadIdx.x; i < n4; i += gridDim.x * blockDim.x) {
        float4 v = p4[i];
        mn = fminf(mn, fminf(fminf(v.x, v.y), fminf(v.z, v.w)));
        mx = fmaxf(mx, fmaxf(fmaxf(v.x, v.y), fmaxf(v.z, v.w)));
    }
    for (int d = 1; d < 64; d <<= 1) {
        mn = fminf(mn, __shfl_xor(mn, d));
        mx = fmaxf(mx, __shfl_xor(mx, d));
    }
    __shared__ float smn[4], smx[4];
    int wv = threadIdx.x >> 6;
    if ((threadIdx.x & 63) == 0) { smn[wv] = mn; smx[wv] = mx; }
    __syncthreads();
    if (threadIdx.x == 0) {
        mn = fminf(fminf(smn[0], smn[1]), fminf(smn[2], smn[3]));
        mx = fmaxf(fmaxf(smx[0], smx[1]), fmaxf(smx[2], smx[3]));
        partials[(t * NB_RED + blockIdx.x) * 2 + 0] = mn;
        partials[(t * NB_RED + blockIdx.x) * 2 + 1] = mx;
    }
}

__global__ void k_minmax_final(const float* __restrict__ partials, const int* __restrict__ nbits,
                               float* __restrict__ params) {
    int t = blockIdx.x;
    int tid = threadIdx.x;
    float mn = partials[(t * NB_RED + tid) * 2 + 0];
    float mx = partials[(t * NB_RED + tid) * 2 + 1];
    for (int d = 1; d < 64; d <<= 1) {
        mn = fminf(mn, __shfl_xor(mn, d));
        mx = fmaxf(mx, __shfl_xor(mx, d));
    }
    __shared__ float smn[4], smx[4];
    int wv = tid >> 6;
    if ((tid & 63) == 0) { smn[wv] = mn; smx[wv] = mx; }
    __syncthreads();
    if (tid == 0) {
        mn = fminf(fminf(smn[0], smn[1]), fminf(smn[2], smn[3]));
        mx = fmaxf(fmaxf(smx[0], smx[1]), fmaxf(smx[2], smx[3]));
        float qmax = (float)((1u << (*nbits)) - 1u);
        params[t * 2 + 0] = mn;
        params[t * 2 + 1] = (mx - mn) / qmax;
    }
}

static __device__ __forceinline__ int block_reduce_i(int v, int tid) {
    for (int d = 1; d < 64; d <<= 1) v += __shfl_xor(v, d);
    __shared__ int sred[4];
    if ((tid & 63) == 0) sred[tid >> 6] = v;
    __syncthreads();
    return sred[0] + sred[1] + sred[2] + sred[3];
}

// -------- quantize x|h -> A8 i8 levels-128, [8192][2048]; row level-sums -----
__global__ void k_quant_A(const float* __restrict__ x, const float* __restrict__ h,
                          const float* __restrict__ params, s8* __restrict__ A8,
                          float* __restrict__ Rax, float* __restrict__ Rah) {
    int b = blockIdx.x;            // 0..16383
    int tsel = b >> 13;            // 0: x, 1: h
    int row = b & 8191;
    const float* src = tsel ? h : x;
    float mn = params[tsel * 2 + 0], s = params[tsel * 2 + 1];
    int t = threadIdx.x;
    float4 v = ((const float4*)(src + (size_t)row * 1024))[t];
    int k0 = (int)fminf(255.f, fmaxf(0.f, rintf((v.x - mn) / s)));
    int k1 = (int)fminf(255.f, fmaxf(0.f, rintf((v.y - mn) / s)));
    int k2 = (int)fminf(255.f, fmaxf(0.f, rintf((v.z - mn) / s)));
    int k3 = (int)fminf(255.f, fmaxf(0.f, rintf((v.w - mn) / s)));
    unsigned p = ((unsigned)((k0 - 128) & 0xff)) | ((unsigned)((k1 - 128) & 0xff) << 8) |
                 ((unsigned)((k2 - 128) & 0xff) << 16) | ((unsigned)((k3 - 128) & 0xff) << 24);
    *(unsigned*)(A8 + (size_t)row * 2048 + tsel * 1024 + t * 4) = p;
    int sum = block_reduce_i(k0 + k1 + k2 + k3 - 512, t);
    if (t == 0) (tsel ? Rah : Rax)[row] = (float)sum;
}

// -------- quantize W_in|W_h -> W8 i8 levels-128, [4096][2048] permuted -------
// prow = (j>>4)*64 + g*16 + (j&15): each 64-col sub-tile = 4 gates of 16 units.
__global__ void k_quant_W(const float* __restrict__ wi, const float* __restrict__ wh,
                          const float* __restrict__ params, s8* __restrict__ W8,
                          float* __restrict__ Rbi, float* __restrict__ Rbh) {
    int b = blockIdx.x;            // 0..8191
    int tsel = b >> 12;            // 0: W_in, 1: W_h
    int row = b & 4095;            // original row g*1024+j
    const float* src = tsel ? wh : wi;
    float mn = params[(2 + tsel) * 2 + 0], s = params[(2 + tsel) * 2 + 1];
    int g = row >> 10, j = row & 1023;
    int prow = (j >> 4) * 64 + g * 16 + (j & 15);
    int t = threadIdx.x;
    float4 v = ((const float4*)(src + (size_t)row * 1024))[t];
    int k0 = (int)fminf(255.f, fmaxf(0.f, rintf((v.x - mn) / s)));
    int k1 = (int)fminf(255.f, fmaxf(0.f, rintf((v.y - mn) / s)));
    int k2 = (int)fminf(255.f, fmaxf(0.f, rintf((v.z - mn) / s)));
    int k3 = (int)fminf(255.f, fmaxf(0.f, rintf((v.w - mn) / s)));
    unsigned p = ((unsigned)((k0 - 128) & 0xff)) | ((unsigned)((k1 - 128) & 0xff) << 8) |
                 ((unsigned)((k2 - 128) & 0xff) << 16) | ((unsigned)((k3 - 128) & 0xff) << 24);
    *(unsigned*)(W8 + (size_t)prow * 2048 + tsel * 1024 + t * 4) = p;
    int sum = block_reduce_i(k0 + k1 + k2 + k3 - 512, t);
    if (t == 0) (tsel ? Rbh : Rbi)[prow] = (float)sum;
}

// ---------------- combined bias in permuted order ----------------
__global__ void k_bias(const float* __restrict__ b_in, const float* __restrict__ b_h,
                       float* __restrict__ bc) {
    int n = blockIdx.x * 256 + threadIdx.x;   // permuted col index
    int j = (n >> 6) * 16 + (n & 15);
    int g = (n >> 4) & 3;
    bc[n] = b_in[g * 1024 + j] + b_h[g * 1024 + j];
}

// ---------------- fused i8 GEMM + LSTM pointwise (NO-LDS, barrier-free) -----
// R4 compute geometry: 128x128 tile, 4 waves (2x2), wave 64x64 = 4x4 frags,
// BK=64 bytes, mfma_i32_16x16x64_i8, 32 K-steps, acc split at k=1024.
// R9 schedule: NO LDS, NO barriers. Each lane loads its MFMA fragments
// directly from global (lane (la,hi) owns row la, k-bytes [hi*16,hi*16+16) of
// each 64B K-chunk -- the fragment mapping validated through R4-R8). 3-deep
// rotating register pipeline ast/bst[3][4]; full unroll makes every index
// compile-time (rule #20). t*64 offsets fold into the 13-bit global_load
// immediate; 8 precomputed frag pointers -> zero per-step address VALU.
// Waves free-run (AITER-style MFMA<->load interleave, compiler-counted
// vmcnt), 2x L2 read amplification absorbed by L2 (13% HBM util).
// XCD decode: bid%8 = XCD owns by-slice (A 2MB L2-resident, W-panel reuse).
__global__ __launch_bounds__(256, 2) void k_gemm_lstm(
    const s8* __restrict__ A8, const s8* __restrict__ W8,
    const float* __restrict__ params, const float* __restrict__ bc,
    const float* __restrict__ Rax, const float* __restrict__ Rah,
    const float* __restrict__ Rbi, const float* __restrict__ Rbh,
    const float* __restrict__ c_in, float* __restrict__ out) {
    const int tid = threadIdx.x;
    const int wave = tid >> 6, lane = tid & 63;
    const int wr = wave >> 1, wc = wave & 1;
    const int la = lane & 15, hi = lane >> 4;

    // XCD-aware tile decode (grid = 2048 1-D)
    const int bid = blockIdx.x;
    const int l = bid >> 3;                   // 0..255 within XCD chunk
    const int bx = l >> 3;                    // 0..31  (N tile)
    const int by = (bid & 7) * 8 + (l & 7);   // 0..63  (M tile)
    const int bm = by * 128, bn = bx * 128;

    // per-lane fragment pointers (k advances via compile-time t*64 immediates)
    const s8* aP[4];
    const s8* bP[4];
#pragma unroll
    for (int m = 0; m < 4; ++m)
        aP[m] = A8 + (size_t)(bm + wr * 64 + m * 16 + la) * 2048 + hi * 16;
#pragma unroll
    for (int n = 0; n < 4; ++n)
        bP[n] = W8 + (size_t)(bn + wc * 64 + n * 16 + la) * 2048 + hi * 16;

    i32x4 acc1[4][4], acc2[4][4];
#pragma unroll
    for (int m = 0; m < 4; m++)
#pragma unroll
        for (int n = 0; n < 4; n++) { acc1[m][n] = (i32x4)0; acc2[m][n] = (i32x4)0; }

    i32x4 ast[3][4], bst[3][4];

#define LOADT(S, T)                                                     \
    do {                                                                \
        _Pragma("unroll") for (int m = 0; m < 4; ++m)                   \
            ast[S][m] = *(const i32x4*)(aP[m] + (T) * 64);              \
        _Pragma("unroll") for (int n = 0; n < 4; ++n)                   \
            bst[S][n] = *(const i32x4*)(bP[n] + (T) * 64);              \
    } while (0)

#define COMPUTET(S, ACC)                                                \
    do {                                                                \
        _Pragma("unroll") for (int m = 0; m < 4; ++m)                   \
            _Pragma("unroll") for (int n = 0; n < 4; ++n)               \
                ACC[m][n] = __builtin_amdgcn_mfma_i32_16x16x64_i8(      \
                    ast[S][m], bst[S][n], ACC[m][n], 0, 0, 0);          \
    } while (0)

    LOADT(0, 0);
    LOADT(1, 1);
#pragma unroll
    for (int t = 0; t < 32; ++t) {
        if (t + 2 < 32) LOADT((t + 2) % 3, t + 2);
        __builtin_amdgcn_s_setprio(1);
        if (t < 16) COMPUTET(t % 3, acc1); else COMPUTET(t % 3, acc2);
        __builtin_amdgcn_s_setprio(0);
    }

#undef LOADT
#undef COMPUTET

    // ---- epilogue: reconstruct gates from integer sums, LSTM pointwise ----
    float mna = params[0], sa = params[1], mnh = params[2], sh = params[3];
    float mni = params[4], si = params[5], mnw = params[6], sw = params[7];
    float za = mna + 128.0f * sa, zi = mni + 128.0f * si;
    float zh = mnh + 128.0f * sh, zw = mnw + 128.0f * sw;
    float C0 = 1024.0f * (za * zi + zh * zw);
    float cax = sa * zi, cah = sh * zw;
    float cbx = si * za, cbh = sw * zh;
    float csx = sa * si, csh = sh * sw;

    const int nb = bn + wc * 64;
    float colt[4];
#pragma unroll
    for (int g = 0; g < 4; ++g) {
        int np = nb + g * 16 + la;
        colt[g] = bc[np] + cbx * Rbi[np] + cbh * Rbh[np] + C0;
    }
    const int ub = (nb >> 6) * 16 + la;   // hidden-unit index

#pragma unroll
    for (int m = 0; m < 4; m++) {
#pragma unroll
        for (int q = 0; q < 4; q++) {
            int row = bm + wr * 64 + m * 16 + 4 * hi + q;
            float rterm = cax * Rax[row] + cah * Rah[row];
            float g0 = colt[0] + rterm + csx * (float)acc1[m][0][q] + csh * (float)acc2[m][0][q];
            float g1 = colt[1] + rterm + csx * (float)acc1[m][1][q] + csh * (float)acc2[m][1][q];
            float g2 = colt[2] + rterm + csx * (float)acc1[m][2][q] + csh * (float)acc2[m][2][q];
            float g3 = colt[3] + rterm + csx * (float)acc1[m][3][q] + csh * (float)acc2[m][3][q];
            float iv = 1.0f / (1.0f + __expf(-g0));
            float fv = 1.0f / (1.0f + __expf(-g1));
            float gv = tanhf(g2);
            float ov = 1.0f / (1.0f + __expf(-g3));
            size_t off = (size_t)row * 1024 + ub;
            float cv = c_in[off];
            float cn = fv * cv + iv * gv;
            float hn = ov * tanhf(cn);
            out[off] = hn;
            out[(size_t)8192 * 1024 + off] = cn;
        }
    }
}

extern "C" void kernel_launch(void* const* d_in, const int* in_sizes, int n_in,
                              void* d_out, int out_size, void* d_ws, size_t ws_size,
                              hipStream_t stream) {
    const float* x = (const float*)d_in[0];
    const float* h = (const float*)d_in[1];
    const float* c = (const float*)d_in[2];
    const float* wi = (const float*)d_in[3];
    const float* bi = (const float*)d_in[4];
    const float* wh = (const float*)d_in[5];
    const float* bh = (const float*)d_in[6];
    const int* nbits = (const int*)d_in[7];
    float* out = (float*)d_out;

    char* ws = (char*)d_ws;
    float* params   = (float*)ws;                   // 8 f32
    float* partials = (float*)(ws + 64);            // 4*256*2 f32
    float* bc  = (float*)(ws + 16384);              // 4096 f32
    float* Rax = (float*)(ws + 32768);              // 8192 f32
    float* Rah = (float*)(ws + 65536);              // 8192 f32
    float* Rbi = (float*)(ws + 98304);              // 4096 f32
    float* Rbh = (float*)(ws + 114688);             // 4096 f32
    s8* A8 = (s8*)(ws + 131072);                    // 8192*2048 i8 = 16MB
    s8* W8 = (s8*)(ws + 131072 + (size_t)16 * 1024 * 1024);  // 4096*2048 i8 = 8MB

    k_minmax_partial<<<dim3(NB_RED, 4), 256, 0, stream>>>(x, h, wi, wh, partials);
    k_minmax_final<<<4, 256, 0, stream>>>(partials, nbits, params);
    k_quant_A<<<16384, 256, 0, stream>>>(x, h, params, A8, Rax, Rah);
    k_quant_W<<<8192, 256, 0, stream>>>(wi, wh, params, W8, Rbi, Rbh);
    k_bias<<<16, 256, 0, stream>>>(bi, bh, bc);
    k_gemm_lstm<<<2048, 256, 0, stream>>>(A8, W8, params, bc, Rax, Rah, Rbi, Rbh, c, out);
}

// Round 10
// 154.892 us; speedup vs baseline: 1.8827x; 1.8827x over previous
//
#include <hip/hip_runtime.h>
#include <hip/hip_bf16.h>

typedef unsigned short u16;
typedef int i32x4 __attribute__((ext_vector_type(4)));
typedef signed char s8;

#define NB_RED 256

// ---------------- min/max reduction (4 tensors) ----------------
__global__ void k_minmax_partial(const float* __restrict__ x, const float* __restrict__ h,
                                 const float* __restrict__ wi, const float* __restrict__ wh,
                                 float* __restrict__ partials) {
    int t = blockIdx.y;
    const float* p = (t == 0) ? x : (t == 1) ? h : (t == 2) ? wi : wh;
    int n4 = ((t < 2) ? (8192 * 1024) : (4096 * 1024)) >> 2;
    float mn = 3.4e38f, mx = -3.4e38f;
    const float4* p4 = (const float4*)p;
    for (int i = blockIdx.x * blockDim.x + threadIdx.x; i < n4; i += gridDim.x * blockDim.x) {
        float4 v = p4[i];
        mn = fminf(mn, fminf(fminf(v.x, v.y), fminf(v.z, v.w)));
        mx = fmaxf(mx, fmaxf(fmaxf(v.x, v.y), fmaxf(v.z, v.w)));
    }
    for (int d = 1; d < 64; d <<= 1) {
        mn = fminf(mn, __shfl_xor(mn, d));
        mx = fmaxf(mx, __shfl_xor(mx, d));
    }
    __shared__ float smn[4], smx[4];
    int wv = threadIdx.x >> 6;
    if ((threadIdx.x & 63) == 0) { smn[wv] = mn; smx[wv] = mx; }
    __syncthreads();
    if (threadIdx.x == 0) {
        mn = fminf(fminf(smn[0], smn[1]), fminf(smn[2], smn[3]));
        mx = fmaxf(fmaxf(smx[0], smx[1]), fmaxf(smx[2], smx[3]));
        partials[(t * NB_RED + blockIdx.x) * 2 + 0] = mn;
        partials[(t * NB_RED + blockIdx.x) * 2 + 1] = mx;
    }
}

__global__ void k_minmax_final(const float* __restrict__ partials, const int* __restrict__ nbits,
                               float* __restrict__ params) {
    int t = blockIdx.x;
    int tid = threadIdx.x;
    float mn = partials[(t * NB_RED + tid) * 2 + 0];
    float mx = partials[(t * NB_RED + tid) * 2 + 1];
    for (int d = 1; d < 64; d <<= 1) {
        mn = fminf(mn, __shfl_xor(mn, d));
        mx = fmaxf(mx, __shfl_xor(mx, d));
    }
    __shared__ float smn[4], smx[4];
    int wv = tid >> 6;
    if ((tid & 63) == 0) { smn[wv] = mn; smx[wv] = mx; }
    __syncthreads();
    if (tid == 0) {
        mn = fminf(fminf(smn[0], smn[1]), fminf(smn[2], smn[3]));
        mx = fmaxf(fmaxf(smx[0], smx[1]), fmaxf(smx[2], smx[3]));
        float qmax = (float)((1u << (*nbits)) - 1u);
        params[t * 2 + 0] = mn;
        params[t * 2 + 1] = (mx - mn) / qmax;
    }
}

static __device__ __forceinline__ int block_reduce_i(int v, int tid) {
    for (int d = 1; d < 64; d <<= 1) v += __shfl_xor(v, d);
    __shared__ int sred[4];
    if ((tid & 63) == 0) sred[tid >> 6] = v;
    __syncthreads();
    return sred[0] + sred[1] + sred[2] + sred[3];
}

// ---- fused quantize (x|h -> A8, W_in|W_h -> W8 permuted) + bias ----
// blocks [0,16384): A rows; [16384,24576): W rows; [24576,24592): bias.
__global__ void k_quant(const float* __restrict__ x, const float* __restrict__ h,
                        const float* __restrict__ wi, const float* __restrict__ wh,
                        const float* __restrict__ params,
                        const float* __restrict__ b_in, const float* __restrict__ b_h,
                        s8* __restrict__ A8, s8* __restrict__ W8,
                        float* __restrict__ Rax, float* __restrict__ Rah,
                        float* __restrict__ Rbi, float* __restrict__ Rbh,
                        float* __restrict__ bc) {
    int b = blockIdx.x;
    int t = threadIdx.x;
    if (b < 16384) {
        int tsel = b >> 13;            // 0: x, 1: h
        int row = b & 8191;
        const float* src = tsel ? h : x;
        float mn = params[tsel * 2 + 0], s = params[tsel * 2 + 1];
        float4 v = ((const float4*)(src + (size_t)row * 1024))[t];
        int k0 = (int)fminf(255.f, fmaxf(0.f, rintf((v.x - mn) / s)));
        int k1 = (int)fminf(255.f, fmaxf(0.f, rintf((v.y - mn) / s)));
        int k2 = (int)fminf(255.f, fmaxf(0.f, rintf((v.z - mn) / s)));
        int k3 = (int)fminf(255.f, fmaxf(0.f, rintf((v.w - mn) / s)));
        unsigned p = ((unsigned)((k0 - 128) & 0xff)) | ((unsigned)((k1 - 128) & 0xff) << 8) |
                     ((unsigned)((k2 - 128) & 0xff) << 16) | ((unsigned)((k3 - 128) & 0xff) << 24);
        *(unsigned*)(A8 + (size_t)row * 2048 + tsel * 1024 + t * 4) = p;
        int sum = block_reduce_i(k0 + k1 + k2 + k3 - 512, t);
        if (t == 0) (tsel ? Rah : Rax)[row] = (float)sum;
    } else if (b < 24576) {
        int bb = b - 16384;
        int tsel = bb >> 12;           // 0: W_in, 1: W_h
        int row = bb & 4095;           // original row g*1024+j
        const float* src = tsel ? wh : wi;
        float mn = params[(2 + tsel) * 2 + 0], s = params[(2 + tsel) * 2 + 1];
        int g = row >> 10, j = row & 1023;
        int prow = (j >> 4) * 64 + g * 16 + (j & 15);
        float4 v = ((const float4*)(src + (size_t)row * 1024))[t];
        int k0 = (int)fminf(255.f, fmaxf(0.f, rintf((v.x - mn) / s)));
        int k1 = (int)fminf(255.f, fmaxf(0.f, rintf((v.y - mn) / s)));
        int k2 = (int)fminf(255.f, fmaxf(0.f, rintf((v.z - mn) / s)));
        int k3 = (int)fminf(255.f, fmaxf(0.f, rintf((v.w - mn) / s)));
        unsigned p = ((unsigned)((k0 - 128) & 0xff)) | ((unsigned)((k1 - 128) & 0xff) << 8) |
                     ((unsigned)((k2 - 128) & 0xff) << 16) | ((unsigned)((k3 - 128) & 0xff) << 24);
        *(unsigned*)(W8 + (size_t)prow * 2048 + tsel * 1024 + t * 4) = p;
        int sum = block_reduce_i(k0 + k1 + k2 + k3 - 512, t);
        if (t == 0) (tsel ? Rbh : Rbi)[prow] = (float)sum;
    } else {
        int n = (b - 24576) * 256 + t;   // permuted col index
        int j = (n >> 6) * 16 + (n & 15);
        int g = (n >> 4) & 3;
        bc[n] = b_in[g * 1024 + j] + b_h[g * 1024 + j];
    }
}

// ---------------- fused i8 GEMM + LSTM pointwise (R8 schedule) ----------------
// 128x128 tile, 4 waves (2x2), wave 64x64 = 4x4 frags, BK=64 bytes,
// mfma_i32_16x16x64_i8, 32 K-steps, acc split at k=1024 (scale exactness).
// 5 LDS buffers (80KB; reg cap = 2 blocks/CU so LDS free), stage 4 tiles
// ahead with compile-time offsets, counted vmcnt(12) steady state, ONE
// barrier per K-step. No setprio (m190: hurts lockstep GEMM).
// XCD decode: bid%8 = XCD owns by-slice (A 2MB L2-resident, W-panel reuse).
// LDS swizzle (0 conflicts measured): phys 16B slot = logical ^ ((row>>1)&3),
// inverse on global source (linear gload_lds dest, rule #21), fwd on ds_read.
__global__ __launch_bounds__(256, 2) void k_gemm_lstm(
    const s8* __restrict__ A8, const s8* __restrict__ W8,
    const float* __restrict__ params, const float* __restrict__ bc,
    const float* __restrict__ Rax, const float* __restrict__ Rah,
    const float* __restrict__ Rbi, const float* __restrict__ Rbh,
    const float* __restrict__ c_in, float* __restrict__ out) {
    __shared__ __align__(16) s8 As[5][8192];
    __shared__ __align__(16) s8 Bs[5][8192];

    const int tid = threadIdx.x;
    const int wave = tid >> 6, lane = tid & 63;
    const int wr = wave >> 1, wc = wave & 1;
    const int la = lane & 15, hi = lane >> 4;

    // XCD-aware tile decode (grid = 2048 1-D)
    const int bid = blockIdx.x;
    const int l = bid >> 3;                   // 0..255 within XCD chunk
    const int bx = l >> 3;                    // 0..31  (N tile)
    const int by = (bid & 7) * 8 + (l & 7);   // 0..63  (M tile)
    const int bm = by * 128, bn = bx * 128;

    const int srow = lane >> 2;                                   // row in 16-row group
    const int skb = (((lane & 3) ^ ((srow >> 1) & 3)) * 16);      // pre-swizzled k-byte
    const int fR = (la >> 1) & 3;                                 // read-side swizzle

    // loop-invariant staging pointers (k advances via compile-time t*64)
    const s8* pA0 = A8 + (size_t)(bm + wave * 16 + srow) * 2048 + skb;
    const s8* pA1 = pA0 + (size_t)64 * 2048;
    const s8* pB0 = W8 + (size_t)(bn + wave * 16 + srow) * 2048 + skb;
    const s8* pB1 = pB0 + (size_t)64 * 2048;

    i32x4 acc1[4][4], acc2[4][4];
#pragma unroll
    for (int m = 0; m < 4; m++)
#pragma unroll
        for (int n = 0; n < 4; n++) { acc1[m][n] = (i32x4)0; acc2[m][n] = (i32x4)0; }

#define STAGE(B, T)                                                                               \
    do {                                                                                          \
        __builtin_amdgcn_global_load_lds(                                                         \
            (const __attribute__((address_space(1))) void*)(pA0 + (T) * 64),                      \
            (__attribute__((address_space(3))) void*)&As[(B)][wave * 1024], 16, 0, 0);            \
        __builtin_amdgcn_global_load_lds(                                                         \
            (const __attribute__((address_space(1))) void*)(pA1 + (T) * 64),                      \
            (__attribute__((address_space(3))) void*)&As[(B)][(4 + wave) * 1024], 16, 0, 0);      \
        __builtin_amdgcn_global_load_lds(                                                         \
            (const __attribute__((address_space(1))) void*)(pB0 + (T) * 64),                      \
            (__attribute__((address_space(3))) void*)&Bs[(B)][wave * 1024], 16, 0, 0);            \
        __builtin_amdgcn_global_load_lds(                                                         \
            (const __attribute__((address_space(1))) void*)(pB1 + (T) * 64),                      \
            (__attribute__((address_space(3))) void*)&Bs[(B)][(4 + wave) * 1024], 16, 0, 0);      \
    } while (0)

#define COMPUTE(B, ACC)                                                                           \
    do {                                                                                          \
        i32x4 af[4], bf[4];                                                                       \
        _Pragma("unroll") for (int m = 0; m < 4; m++)                                             \
            af[m] = *(const i32x4*)&As[(B)][(wr * 64 + m * 16 + la) * 64 + ((hi ^ fR) * 16)];     \
        _Pragma("unroll") for (int n = 0; n < 4; n++)                                             \
            bf[n] = *(const i32x4*)&Bs[(B)][(wc * 64 + n * 16 + la) * 64 + ((hi ^ fR) * 16)];     \
        _Pragma("unroll") for (int m = 0; m < 4; m++)                                             \
            _Pragma("unroll") for (int n = 0; n < 4; n++)                                         \
                ACC[m][n] = __builtin_amdgcn_mfma_i32_16x16x64_i8(af[m], bf[n], ACC[m][n], 0, 0, 0); \
    } while (0)

    // prologue: 4 tiles in flight (16 loads/wave); wait tile 0 (leave 12)
    STAGE(0, 0);
    STAGE(1, 1);
    STAGE(2, 2);
    STAGE(3, 3);
    asm volatile("s_waitcnt vmcnt(12)" ::: "memory");
    __builtin_amdgcn_s_barrier();

#pragma unroll
    for (int t = 0; t < 32; ++t) {
        if (t < 28) STAGE((t + 4) % 5, t + 4);
        if (t < 16) COMPUTE(t % 5, acc1); else COMPUTE(t % 5, acc2);
        if (t < 28) { asm volatile("s_waitcnt vmcnt(12)" ::: "memory"); }
        else if (t == 28) { asm volatile("s_waitcnt vmcnt(8)" ::: "memory"); }
        else if (t == 29) { asm volatile("s_waitcnt vmcnt(4)" ::: "memory"); }
        else if (t == 30) { asm volatile("s_waitcnt vmcnt(0)" ::: "memory"); }
        if (t < 31) __builtin_amdgcn_s_barrier();
    }

#undef STAGE
#undef COMPUTE

    // ---- epilogue: reconstruct gates from integer sums, LSTM pointwise ----
    float mna = params[0], sa = params[1], mnh = params[2], sh = params[3];
    float mni = params[4], si = params[5], mnw = params[6], sw = params[7];
    float za = mna + 128.0f * sa, zi = mni + 128.0f * si;
    float zh = mnh + 128.0f * sh, zw = mnw + 128.0f * sw;
    float C0 = 1024.0f * (za * zi + zh * zw);
    float cax = sa * zi, cah = sh * zw;
    float cbx = si * za, cbh = sw * zh;
    float csx = sa * si, csh = sh * sw;

    const int nb = bn + wc * 64;
    float colt[4];
#pragma unroll
    for (int g = 0; g < 4; ++g) {
        int np = nb + g * 16 + la;
        colt[g] = bc[np] + cbx * Rbi[np] + cbh * Rbh[np] + C0;
    }
    const int ub = (nb >> 6) * 16 + la;   // hidden-unit index

#pragma unroll
    for (int m = 0; m < 4; m++) {
#pragma unroll
        for (int q = 0; q < 4; q++) {
            int row = bm + wr * 64 + m * 16 + 4 * hi + q;
            float rterm = cax * Rax[row] + cah * Rah[row];
            float g0 = colt[0] + rterm + csx * (float)acc1[m][0][q] + csh * (float)acc2[m][0][q];
            float g1 = colt[1] + rterm + csx * (float)acc1[m][1][q] + csh * (float)acc2[m][1][q];
            float g2 = colt[2] + rterm + csx * (float)acc1[m][2][q] + csh * (float)acc2[m][2][q];
            float g3 = colt[3] + rterm + csx * (float)acc1[m][3][q] + csh * (float)acc2[m][3][q];
            float iv = 1.0f / (1.0f + __expf(-g0));
            float fv = 1.0f / (1.0f + __expf(-g1));
            float gv = tanhf(g2);
            float ov = 1.0f / (1.0f + __expf(-g3));
            size_t off = (size_t)row * 1024 + ub;
            float cv = c_in[off];
            float cn = fv * cv + iv * gv;
            float hn = ov * tanhf(cn);
            out[off] = hn;
            out[(size_t)8192 * 1024 + off] = cn;
        }
    }
}

extern "C" void kernel_launch(void* const* d_in, const int* in_sizes, int n_in,
                              void* d_out, int out_size, void* d_ws, size_t ws_size,
                              hipStream_t stream) {
    const float* x = (const float*)d_in[0];
    const float* h = (const float*)d_in[1];
    const float* c = (const float*)d_in[2];
    const float* wi = (const float*)d_in[3];
    const float* bi = (const float*)d_in[4];
    const float* wh = (const float*)d_in[5];
    const float* bh = (const float*)d_in[6];
    const int* nbits = (const int*)d_in[7];
    float* out = (float*)d_out;

    char* ws = (char*)d_ws;
    float* params   = (float*)ws;                   // 8 f32
    float* partials = (float*)(ws + 64);            // 4*256*2 f32
    float* bc  = (float*)(ws + 16384);              // 4096 f32
    float* Rax = (float*)(ws + 32768);              // 8192 f32
    float* Rah = (float*)(ws + 65536);              // 8192 f32
    float* Rbi = (float*)(ws + 98304);              // 4096 f32
    float* Rbh = (float*)(ws + 114688);             // 4096 f32
    s8* A8 = (s8*)(ws + 131072);                    // 8192*2048 i8 = 16MB
    s8* W8 = (s8*)(ws + 131072 + (size_t)16 * 1024 * 1024);  // 4096*2048 i8 = 8MB

    k_minmax_partial<<<dim3(NB_RED, 4), 256, 0, stream>>>(x, h, wi, wh, partials);
    k_minmax_final<<<4, 256, 0, stream>>>(partials, nbits, params);
    k_quant<<<24592, 256, 0, stream>>>(x, h, wi, wh, params, bi, bh,
                                       A8, W8, Rax, Rah, Rbi, Rbh, bc);
    k_gemm_lstm<<<2048, 256, 0, stream>>>(A8, W8, params, bc, Rax, Rah, Rbi, Rbh, c, out);
}

// Round 11
// 145.810 us; speedup vs baseline: 2.0000x; 1.0623x over previous
//
#include <hip/hip_runtime.h>
#include <hip/hip_bf16.h>

typedef unsigned short u16;
typedef int i32x4 __attribute__((ext_vector_type(4)));
typedef signed char s8;

#define NB_RED 256

// ---------------- min/max reduction (4 tensors) ----------------
__global__ void k_minmax_partial(const float* __restrict__ x, const float* __restrict__ h,
                                 const float* __restrict__ wi, const float* __restrict__ wh,
                                 float* __restrict__ partials) {
    int t = blockIdx.y;
    const float* p = (t == 0) ? x : (t == 1) ? h : (t == 2) ? wi : wh;
    int n4 = ((t < 2) ? (8192 * 1024) : (4096 * 1024)) >> 2;
    float mn = 3.4e38f, mx = -3.4e38f;
    const float4* p4 = (const float4*)p;
    for (int i = blockIdx.x * blockDim.x + threadIdx.x; i < n4; i += gridDim.x * blockDim.x) {
        float4 v = p4[i];
        mn = fminf(mn, fminf(fminf(v.x, v.y), fminf(v.z, v.w)));
        mx = fmaxf(mx, fmaxf(fmaxf(v.x, v.y), fmaxf(v.z, v.w)));
    }
    for (int d = 1; d < 64; d <<= 1) {
        mn = fminf(mn, __shfl_xor(mn, d));
        mx = fmaxf(mx, __shfl_xor(mx, d));
    }
    __shared__ float smn[4], smx[4];
    int wv = threadIdx.x >> 6;
    if ((threadIdx.x & 63) == 0) { smn[wv] = mn; smx[wv] = mx; }
    __syncthreads();
    if (threadIdx.x == 0) {
        mn = fminf(fminf(smn[0], smn[1]), fminf(smn[2], smn[3]));
        mx = fmaxf(fmaxf(smx[0], smx[1]), fmaxf(smx[2], smx[3]));
        partials[(t * NB_RED + blockIdx.x) * 2 + 0] = mn;
        partials[(t * NB_RED + blockIdx.x) * 2 + 1] = mx;
    }
}

__global__ void k_minmax_final(const float* __restrict__ partials, const int* __restrict__ nbits,
                               float* __restrict__ params) {
    int t = blockIdx.x;
    int tid = threadIdx.x;
    float mn = partials[(t * NB_RED + tid) * 2 + 0];
    float mx = partials[(t * NB_RED + tid) * 2 + 1];
    for (int d = 1; d < 64; d <<= 1) {
        mn = fminf(mn, __shfl_xor(mn, d));
        mx = fmaxf(mx, __shfl_xor(mx, d));
    }
    __shared__ float smn[4], smx[4];
    int wv = tid >> 6;
    if ((tid & 63) == 0) { smn[wv] = mn; smx[wv] = mx; }
    __syncthreads();
    if (tid == 0) {
        mn = fminf(fminf(smn[0], smn[1]), fminf(smn[2], smn[3]));
        mx = fmaxf(fmaxf(smx[0], smx[1]), fmaxf(smx[2], smx[3]));
        float qmax = (float)((1u << (*nbits)) - 1u);
        params[t * 2 + 0] = mn;
        params[t * 2 + 1] = (mx - mn) / qmax;
    }
}

static __device__ __forceinline__ int block_reduce_i(int v, int tid) {
    for (int d = 1; d < 64; d <<= 1) v += __shfl_xor(v, d);
    __shared__ int sred[4];
    if ((tid & 63) == 0) sred[tid >> 6] = v;
    __syncthreads();
    return sred[0] + sred[1] + sred[2] + sred[3];
}

// ---- fused quantize (x|h -> A8, W_in|W_h -> W8 permuted) + bias ----
// blocks [0,16384): A rows; [16384,24576): W rows; [24576,24592): bias.
__global__ void k_quant(const float* __restrict__ x, const float* __restrict__ h,
                        const float* __restrict__ wi, const float* __restrict__ wh,
                        const float* __restrict__ params,
                        const float* __restrict__ b_in, const float* __restrict__ b_h,
                        s8* __restrict__ A8, s8* __restrict__ W8,
                        float* __restrict__ Rax, float* __restrict__ Rah,
                        float* __restrict__ Rbi, float* __restrict__ Rbh,
                        float* __restrict__ bc) {
    int b = blockIdx.x;
    int t = threadIdx.x;
    if (b < 16384) {
        int tsel = b >> 13;            // 0: x, 1: h
        int row = b & 8191;
        const float* src = tsel ? h : x;
        float mn = params[tsel * 2 + 0], s = params[tsel * 2 + 1];
        float4 v = ((const float4*)(src + (size_t)row * 1024))[t];
        int k0 = (int)fminf(255.f, fmaxf(0.f, rintf((v.x - mn) / s)));
        int k1 = (int)fminf(255.f, fmaxf(0.f, rintf((v.y - mn) / s)));
        int k2 = (int)fminf(255.f, fmaxf(0.f, rintf((v.z - mn) / s)));
        int k3 = (int)fminf(255.f, fmaxf(0.f, rintf((v.w - mn) / s)));
        unsigned p = ((unsigned)((k0 - 128) & 0xff)) | ((unsigned)((k1 - 128) & 0xff) << 8) |
                     ((unsigned)((k2 - 128) & 0xff) << 16) | ((unsigned)((k3 - 128) & 0xff) << 24);
        *(unsigned*)(A8 + (size_t)row * 2048 + tsel * 1024 + t * 4) = p;
        int sum = block_reduce_i(k0 + k1 + k2 + k3 - 512, t);
        if (t == 0) (tsel ? Rah : Rax)[row] = (float)sum;
    } else if (b < 24576) {
        int bb = b - 16384;
        int tsel = bb >> 12;           // 0: W_in, 1: W_h
        int row = bb & 4095;           // original row g*1024+j
        const float* src = tsel ? wh : wi;
        float mn = params[(2 + tsel) * 2 + 0], s = params[(2 + tsel) * 2 + 1];
        int g = row >> 10, j = row & 1023;
        int prow = (j >> 4) * 64 + g * 16 + (j & 15);
        float4 v = ((const float4*)(src + (size_t)row * 1024))[t];
        int k0 = (int)fminf(255.f, fmaxf(0.f, rintf((v.x - mn) / s)));
        int k1 = (int)fminf(255.f, fmaxf(0.f, rintf((v.y - mn) / s)));
        int k2 = (int)fminf(255.f, fmaxf(0.f, rintf((v.z - mn) / s)));
        int k3 = (int)fminf(255.f, fmaxf(0.f, rintf((v.w - mn) / s)));
        unsigned p = ((unsigned)((k0 - 128) & 0xff)) | ((unsigned)((k1 - 128) & 0xff) << 8) |
                     ((unsigned)((k2 - 128) & 0xff) << 16) | ((unsigned)((k3 - 128) & 0xff) << 24);
        *(unsigned*)(W8 + (size_t)prow * 2048 + tsel * 1024 + t * 4) = p;
        int sum = block_reduce_i(k0 + k1 + k2 + k3 - 512, t);
        if (t == 0) (tsel ? Rbh : Rbi)[prow] = (float)sum;
    } else {
        int n = (b - 24576) * 256 + t;   // permuted col index
        int j = (n >> 6) * 16 + (n & 15);
        int g = (n >> 4) & 3;
        bc[n] = b_in[g * 1024 + j] + b_h[g * 1024 + j];
    }
}

// ---------------- fused i8 GEMM + LSTM pointwise ----------------
// R8 geometry: 128x128 tile, 4 waves (2x2), wave 64x64 = 4x4 frags, BK=64B,
// mfma_i32_16x16x64_i8, 32 K-steps, XCD decode, validated swizzle.
// R11 occupancy unlock: SINGLE i32 accumulator. Exactness preserved via
//   csx*S1 + csh*S2 = csh*(r*S1 + S2), r = csx/csh:
// accumulate x-half (t<16), rescale acc = rint(r*acc) ONCE in-register,
// continue h-half into the same acc; epilogue scales by csh. Error <= ~1
// integer unit * csh ~ 6e-5 per gate (threshold 0.107).
// 64 freed regs -> __launch_bounds__(256,3) -> 3 blocks/CU; LDS cut to
// 3 buffers (48KB, 160/48=3.3) staging 2 ahead, steady vmcnt(4).
// LDS swizzle (0 conflicts measured): phys 16B slot = logical ^ ((row>>1)&3),
// inverse on global source (linear gload_lds dest, rule #21), fwd on ds_read.
__global__ __launch_bounds__(256, 3) void k_gemm_lstm(
    const s8* __restrict__ A8, const s8* __restrict__ W8,
    const float* __restrict__ params, const float* __restrict__ bc,
    const float* __restrict__ Rax, const float* __restrict__ Rah,
    const float* __restrict__ Rbi, const float* __restrict__ Rbh,
    const float* __restrict__ c_in, float* __restrict__ out) {
    __shared__ __align__(16) s8 As[3][8192];
    __shared__ __align__(16) s8 Bs[3][8192];

    const int tid = threadIdx.x;
    const int wave = tid >> 6, lane = tid & 63;
    const int wr = wave >> 1, wc = wave & 1;
    const int la = lane & 15, hi = lane >> 4;

    // XCD-aware tile decode (grid = 2048 1-D)
    const int bid = blockIdx.x;
    const int l = bid >> 3;                   // 0..255 within XCD chunk
    const int bx = l >> 3;                    // 0..31  (N tile)
    const int by = (bid & 7) * 8 + (l & 7);   // 0..63  (M tile)
    const int bm = by * 128, bn = bx * 128;

    const int srow = lane >> 2;                                   // row in 16-row group
    const int skb = (((lane & 3) ^ ((srow >> 1) & 3)) * 16);      // pre-swizzled k-byte
    const int fR = (la >> 1) & 3;                                 // read-side swizzle

    // quant params (needed for mid-loop rescale ratio)
    const float sa = params[1], sh = params[3], si = params[5], sw = params[7];
    const float csx = sa * si, csh = sh * sw;
    const float r = csx / csh;

    // loop-invariant staging pointers (k advances via compile-time t*64)
    const s8* pA0 = A8 + (size_t)(bm + wave * 16 + srow) * 2048 + skb;
    const s8* pA1 = pA0 + (size_t)64 * 2048;
    const s8* pB0 = W8 + (size_t)(bn + wave * 16 + srow) * 2048 + skb;
    const s8* pB1 = pB0 + (size_t)64 * 2048;

    i32x4 acc[4][4];
#pragma unroll
    for (int m = 0; m < 4; m++)
#pragma unroll
        for (int n = 0; n < 4; n++) acc[m][n] = (i32x4)0;

#define STAGE(B, T)                                                                               \
    do {                                                                                          \
        __builtin_amdgcn_global_load_lds(                                                         \
            (const __attribute__((address_space(1))) void*)(pA0 + (T) * 64),                      \
            (__attribute__((address_space(3))) void*)&As[(B)][wave * 1024], 16, 0, 0);            \
        __builtin_amdgcn_global_load_lds(                                                         \
            (const __attribute__((address_space(1))) void*)(pA1 + (T) * 64),                      \
            (__attribute__((address_space(3))) void*)&As[(B)][(4 + wave) * 1024], 16, 0, 0);      \
        __builtin_amdgcn_global_load_lds(                                                         \
            (const __attribute__((address_space(1))) void*)(pB0 + (T) * 64),                      \
            (__attribute__((address_space(3))) void*)&Bs[(B)][wave * 1024], 16, 0, 0);            \
        __builtin_amdgcn_global_load_lds(                                                         \
            (const __attribute__((address_space(1))) void*)(pB1 + (T) * 64),                      \
            (__attribute__((address_space(3))) void*)&Bs[(B)][(4 + wave) * 1024], 16, 0, 0);      \
    } while (0)

#define COMPUTE(B)                                                                                \
    do {                                                                                          \
        i32x4 af[4], bf[4];                                                                       \
        _Pragma("unroll") for (int m = 0; m < 4; m++)                                             \
            af[m] = *(const i32x4*)&As[(B)][(wr * 64 + m * 16 + la) * 64 + ((hi ^ fR) * 16)];     \
        _Pragma("unroll") for (int n = 0; n < 4; n++)                                             \
            bf[n] = *(const i32x4*)&Bs[(B)][(wc * 64 + n * 16 + la) * 64 + ((hi ^ fR) * 16)];     \
        _Pragma("unroll") for (int m = 0; m < 4; m++)                                             \
            _Pragma("unroll") for (int n = 0; n < 4; n++)                                         \
                acc[m][n] = __builtin_amdgcn_mfma_i32_16x16x64_i8(af[m], bf[n], acc[m][n], 0, 0, 0); \
    } while (0)

    // prologue: tiles 0,1 in flight (8 loads/wave); wait tile 0 (leave 4)
    STAGE(0, 0);
    STAGE(1, 1);
    asm volatile("s_waitcnt vmcnt(4)" ::: "memory");
    __builtin_amdgcn_s_barrier();

#pragma unroll
    for (int t = 0; t < 32; ++t) {
        if (t < 30) STAGE((t + 2) % 3, t + 2);
        if (t == 16) {
            // fold x-half into h-half scale: acc = rint(r * acc)
#pragma unroll
            for (int m = 0; m < 4; m++)
#pragma unroll
                for (int n = 0; n < 4; n++)
#pragma unroll
                    for (int q = 0; q < 4; q++)
                        acc[m][n][q] = (int)rintf((float)acc[m][n][q] * r);
        }
        COMPUTE(t % 3);
        if (t < 30) { asm volatile("s_waitcnt vmcnt(4)" ::: "memory"); }
        else if (t == 30) { asm volatile("s_waitcnt vmcnt(0)" ::: "memory"); }
        if (t < 31) __builtin_amdgcn_s_barrier();
    }

#undef STAGE
#undef COMPUTE

    // ---- epilogue: reconstruct gates from integer sums, LSTM pointwise ----
    float mna = params[0], mnh = params[2], mni = params[4], mnw = params[6];
    float za = mna + 128.0f * sa, zi = mni + 128.0f * si;
    float zh = mnh + 128.0f * sh, zw = mnw + 128.0f * sw;
    float C0 = 1024.0f * (za * zi + zh * zw);
    float cax = sa * zi, cah = sh * zw;
    float cbx = si * za, cbh = sw * zh;

    const int nb = bn + wc * 64;
    float colt[4];
#pragma unroll
    for (int g = 0; g < 4; ++g) {
        int np = nb + g * 16 + la;
        colt[g] = bc[np] + cbx * Rbi[np] + cbh * Rbh[np] + C0;
    }
    const int ub = (nb >> 6) * 16 + la;   // hidden-unit index

#pragma unroll
    for (int m = 0; m < 4; m++) {
#pragma unroll
        for (int q = 0; q < 4; q++) {
            int row = bm + wr * 64 + m * 16 + 4 * hi + q;
            float rterm = cax * Rax[row] + cah * Rah[row];
            float g0 = colt[0] + rterm + csh * (float)acc[m][0][q];
            float g1 = colt[1] + rterm + csh * (float)acc[m][1][q];
            float g2 = colt[2] + rterm + csh * (float)acc[m][2][q];
            float g3 = colt[3] + rterm + csh * (float)acc[m][3][q];
            float iv = 1.0f / (1.0f + __expf(-g0));
            float fv = 1.0f / (1.0f + __expf(-g1));
            float gv = tanhf(g2);
            float ov = 1.0f / (1.0f + __expf(-g3));
            size_t off = (size_t)row * 1024 + ub;
            float cv = c_in[off];
            float cn = fv * cv + iv * gv;
            float hn = ov * tanhf(cn);
            out[off] = hn;
            out[(size_t)8192 * 1024 + off] = cn;
        }
    }
}

extern "C" void kernel_launch(void* const* d_in, const int* in_sizes, int n_in,
                              void* d_out, int out_size, void* d_ws, size_t ws_size,
                              hipStream_t stream) {
    const float* x = (const float*)d_in[0];
    const float* h = (const float*)d_in[1];
    const float* c = (const float*)d_in[2];
    const float* wi = (const float*)d_in[3];
    const float* bi = (const float*)d_in[4];
    const float* wh = (const float*)d_in[5];
    const float* bh = (const float*)d_in[6];
    const int* nbits = (const int*)d_in[7];
    float* out = (float*)d_out;

    char* ws = (char*)d_ws;
    float* params   = (float*)ws;                   // 8 f32
    float* partials = (float*)(ws + 64);            // 4*256*2 f32
    float* bc  = (float*)(ws + 16384);              // 4096 f32
    float* Rax = (float*)(ws + 32768);              // 8192 f32
    float* Rah = (float*)(ws + 65536);              // 8192 f32
    float* Rbi = (float*)(ws + 98304);              // 4096 f32
    float* Rbh = (float*)(ws + 114688);             // 4096 f32
    s8* A8 = (s8*)(ws + 131072);                    // 8192*2048 i8 = 16MB
    s8* W8 = (s8*)(ws + 131072 + (size_t)16 * 1024 * 1024);  // 4096*2048 i8 = 8MB

    k_minmax_partial<<<dim3(NB_RED, 4), 256, 0, stream>>>(x, h, wi, wh, partials);
    k_minmax_final<<<4, 256, 0, stream>>>(partials, nbits, params);
    k_quant<<<24592, 256, 0, stream>>>(x, h, wi, wh, params, bi, bh,
                                       A8, W8, Rax, Rah, Rbi, Rbh, bc);
    k_gemm_lstm<<<2048, 256, 0, stream>>>(A8, W8, params, bc, Rax, Rah, Rbi, Rbh, c, out);
}

// Round 12
// 140.151 us; speedup vs baseline: 2.0807x; 1.0404x over previous
//
#include <hip/hip_runtime.h>
#include <hip/hip_bf16.h>

typedef unsigned short u16;
typedef int i32x4 __attribute__((ext_vector_type(4)));
typedef signed char s8;

#define NB_RED 256

// ---------------- min/max reduction (4 tensors) ----------------
__global__ void k_minmax_partial(const float* __restrict__ x, const float* __restrict__ h,
                                 const float* __restrict__ wi, const float* __restrict__ wh,
                                 float* __restrict__ partials) {
    int t = blockIdx.y;
    const float* p = (t == 0) ? x : (t == 1) ? h : (t == 2) ? wi : wh;
    int n4 = ((t < 2) ? (8192 * 1024) : (4096 * 1024)) >> 2;
    float mn = 3.4e38f, mx = -3.4e38f;
    const float4* p4 = (const float4*)p;
    for (int i = blockIdx.x * blockDim.x + threadIdx.x; i < n4; i += gridDim.x * blockDim.x) {
        float4 v = p4[i];
        mn = fminf(mn, fminf(fminf(v.x, v.y), fminf(v.z, v.w)));
        mx = fmaxf(mx, fmaxf(fmaxf(v.x, v.y), fmaxf(v.z, v.w)));
    }
    for (int d = 1; d < 64; d <<= 1) {
        mn = fminf(mn, __shfl_xor(mn, d));
        mx = fmaxf(mx, __shfl_xor(mx, d));
    }
    __shared__ float smn[4], smx[4];
    int wv = threadIdx.x >> 6;
    if ((threadIdx.x & 63) == 0) { smn[wv] = mn; smx[wv] = mx; }
    __syncthreads();
    if (threadIdx.x == 0) {
        mn = fminf(fminf(smn[0], smn[1]), fminf(smn[2], smn[3]));
        mx = fmaxf(fmaxf(smx[0], smx[1]), fmaxf(smx[2], smx[3]));
        partials[(t * NB_RED + blockIdx.x) * 2 + 0] = mn;
        partials[(t * NB_RED + blockIdx.x) * 2 + 1] = mx;
    }
}

__global__ void k_minmax_final(const float* __restrict__ partials, const int* __restrict__ nbits,
                               float* __restrict__ params) {
    int t = blockIdx.x;
    int tid = threadIdx.x;
    float mn = partials[(t * NB_RED + tid) * 2 + 0];
    float mx = partials[(t * NB_RED + tid) * 2 + 1];
    for (int d = 1; d < 64; d <<= 1) {
        mn = fminf(mn, __shfl_xor(mn, d));
        mx = fmaxf(mx, __shfl_xor(mx, d));
    }
    __shared__ float smn[4], smx[4];
    int wv = tid >> 6;
    if ((tid & 63) == 0) { smn[wv] = mn; smx[wv] = mx; }
    __syncthreads();
    if (tid == 0) {
        mn = fminf(fminf(smn[0], smn[1]), fminf(smn[2], smn[3]));
        mx = fmaxf(fmaxf(smx[0], smx[1]), fmaxf(smx[2], smx[3]));
        float qmax = (float)((1u << (*nbits)) - 1u);
        params[t * 2 + 0] = mn;
        params[t * 2 + 1] = (mx - mn) / qmax;
    }
}

static __device__ __forceinline__ int block_reduce_i(int v, int tid) {
    for (int d = 1; d < 64; d <<= 1) v += __shfl_xor(v, d);
    __shared__ int sred[4];
    if ((tid & 63) == 0) sred[tid >> 6] = v;
    __syncthreads();
    return sred[0] + sred[1] + sred[2] + sred[3];
}

// ---- fused quantize (x|h -> A8, W_in|W_h -> W8 permuted) + bias ----
// blocks [0,16384): A rows; [16384,24576): W rows; [24576,24592): bias.
__global__ void k_quant(const float* __restrict__ x, const float* __restrict__ h,
                        const float* __restrict__ wi, const float* __restrict__ wh,
                        const float* __restrict__ params,
                        const float* __restrict__ b_in, const float* __restrict__ b_h,
                        s8* __restrict__ A8, s8* __restrict__ W8,
                        float* __restrict__ Rax, float* __restrict__ Rah,
                        float* __restrict__ Rbi, float* __restrict__ Rbh,
                        float* __restrict__ bc) {
    int b = blockIdx.x;
    int t = threadIdx.x;
    if (b < 16384) {
        int tsel = b >> 13;            // 0: x, 1: h
        int row = b & 8191;
        const float* src = tsel ? h : x;
        float mn = params[tsel * 2 + 0], s = params[tsel * 2 + 1];
        float4 v = ((const float4*)(src + (size_t)row * 1024))[t];
        int k0 = (int)fminf(255.f, fmaxf(0.f, rintf((v.x - mn) / s)));
        int k1 = (int)fminf(255.f, fmaxf(0.f, rintf((v.y - mn) / s)));
        int k2 = (int)fminf(255.f, fmaxf(0.f, rintf((v.z - mn) / s)));
        int k3 = (int)fminf(255.f, fmaxf(0.f, rintf((v.w - mn) / s)));
        unsigned p = ((unsigned)((k0 - 128) & 0xff)) | ((unsigned)((k1 - 128) & 0xff) << 8) |
                     ((unsigned)((k2 - 128) & 0xff) << 16) | ((unsigned)((k3 - 128) & 0xff) << 24);
        *(unsigned*)(A8 + (size_t)row * 2048 + tsel * 1024 + t * 4) = p;
        int sum = block_reduce_i(k0 + k1 + k2 + k3 - 512, t);
        if (t == 0) (tsel ? Rah : Rax)[row] = (float)sum;
    } else if (b < 24576) {
        int bb = b - 16384;
        int tsel = bb >> 12;           // 0: W_in, 1: W_h
        int row = bb & 4095;           // original row g*1024+j
        const float* src = tsel ? wh : wi;
        float mn = params[(2 + tsel) * 2 + 0], s = params[(2 + tsel) * 2 + 1];
        int g = row >> 10, j = row & 1023;
        int prow = (j >> 4) * 64 + g * 16 + (j & 15);
        float4 v = ((const float4*)(src + (size_t)row * 1024))[t];
        int k0 = (int)fminf(255.f, fmaxf(0.f, rintf((v.x - mn) / s)));
        int k1 = (int)fminf(255.f, fmaxf(0.f, rintf((v.y - mn) / s)));
        int k2 = (int)fminf(255.f, fmaxf(0.f, rintf((v.z - mn) / s)));
        int k3 = (int)fminf(255.f, fmaxf(0.f, rintf((v.w - mn) / s)));
        unsigned p = ((unsigned)((k0 - 128) & 0xff)) | ((unsigned)((k1 - 128) & 0xff) << 8) |
                     ((unsigned)((k2 - 128) & 0xff) << 16) | ((unsigned)((k3 - 128) & 0xff) << 24);
        *(unsigned*)(W8 + (size_t)prow * 2048 + tsel * 1024 + t * 4) = p;
        int sum = block_reduce_i(k0 + k1 + k2 + k3 - 512, t);
        if (t == 0) (tsel ? Rbh : Rbi)[prow] = (float)sum;
    } else {
        int n = (b - 24576) * 256 + t;   // permuted col index
        int j = (n >> 6) * 16 + (n & 15);
        int g = (n >> 4) & 3;
        bc[n] = b_in[g * 1024 + j] + b_h[g * 1024 + j];
    }
}

// ---------------- fused i8 GEMM + LSTM pointwise (256x256 tile) --------------
// 256x256 tile, 512 thr = 8 waves (2M x 4N), wave 128x64 = 8x4 frags 16x16,
// BK=64 bytes, mfma_i32_16x16x64_i8, 32 K-tiles. Single i32 accumulator:
// x-half accumulated for t<16, acc = rint(r*acc) once at t==16 (r=csx/csh),
// h-half continues in-place; epilogue scales by csh (R11-validated).
// 4-buffer LDS ring (128KB -> 1 block/CU), stage 2 tiles ahead, counted
// vmcnt(4) steady state (never 0 until tail), ONE s_barrier per K-tile.
// Arithmetic intensity 2x the 128^2 family: 32 MFMA per 12 ds_read_b128/wave.
// Swizzle (same algebra as R6/R11, measured 0 conflicts): phys 16B slot =
// logical ^ ((row>>1)&3); inverse on global source (linear gload_lds dest,
// rule #21), forward on ds_read. Staging: thread tid covers row tid>>2 and
// row 128+(tid>>2); both reduce to skb = ((tid&3)^((tid>>3)&3))*16.
// XCD decode (grid 512): xcd=bid&7 owns a 4-M-tile slab (A 2MB L2-resident);
// bx sweeps slow -> 4 consecutive blocks share the B-panel.
__global__ __launch_bounds__(512, 2) void k_gemm_lstm(
    const s8* __restrict__ A8, const s8* __restrict__ W8,
    const float* __restrict__ params, const float* __restrict__ bc,
    const float* __restrict__ Rax, const float* __restrict__ Rah,
    const float* __restrict__ Rbi, const float* __restrict__ Rbh,
    const float* __restrict__ c_in, float* __restrict__ out) {
    __shared__ __align__(16) s8 As[4][16384];
    __shared__ __align__(16) s8 Bs[4][16384];

    const int tid = threadIdx.x;
    const int wave = tid >> 6, lane = tid & 63;
    const int wr = wave >> 2, wc = wave & 3;     // 2x4 wave grid
    const int la = lane & 15, hi = lane >> 4;

    // XCD-aware tile decode (grid = 512 1-D; M-tiles 32, N-tiles 16)
    const int bid = blockIdx.x;
    const int xcd = bid & 7, l = bid >> 3;       // l in 0..63
    const int bx = l >> 2;                       // 0..15 (N tile, sweeps slow)
    const int by = xcd * 4 + (l & 3);            // 0..31 (M tile)
    const int bm = by * 256, bn = bx * 256;

    const int skb = (((tid & 3) ^ ((tid >> 3) & 3)) * 16);   // staging swizzled k-byte
    const int fR = (la >> 1) & 3;                            // read-side swizzle

    const float sa = params[1], sh = params[3], si = params[5], sw = params[7];
    const float csx = sa * si, csh = sh * sw;
    const float r = csx / csh;

    // staging pointers: thread covers rows tid>>2 and 128+(tid>>2)
    const s8* pA0 = A8 + (size_t)(bm + (tid >> 2)) * 2048 + skb;
    const s8* pA1 = pA0 + (size_t)128 * 2048;
    const s8* pB0 = W8 + (size_t)(bn + (tid >> 2)) * 2048 + skb;
    const s8* pB1 = pB0 + (size_t)128 * 2048;

    i32x4 acc[8][4];
#pragma unroll
    for (int m = 0; m < 8; m++)
#pragma unroll
        for (int n = 0; n < 4; n++) acc[m][n] = (i32x4)0;

#define STAGE(B, T)                                                                               \
    do {                                                                                          \
        __builtin_amdgcn_global_load_lds(                                                         \
            (const __attribute__((address_space(1))) void*)(pA0 + (T) * 64),                      \
            (__attribute__((address_space(3))) void*)&As[(B)][wave * 1024], 16, 0, 0);            \
        __builtin_amdgcn_global_load_lds(                                                         \
            (const __attribute__((address_space(1))) void*)(pA1 + (T) * 64),                      \
            (__attribute__((address_space(3))) void*)&As[(B)][(8 + wave) * 1024], 16, 0, 0);      \
        __builtin_amdgcn_global_load_lds(                                                         \
            (const __attribute__((address_space(1))) void*)(pB0 + (T) * 64),                      \
            (__attribute__((address_space(3))) void*)&Bs[(B)][wave * 1024], 16, 0, 0);            \
        __builtin_amdgcn_global_load_lds(                                                         \
            (const __attribute__((address_space(1))) void*)(pB1 + (T) * 64),                      \
            (__attribute__((address_space(3))) void*)&Bs[(B)][(8 + wave) * 1024], 16, 0, 0);      \
    } while (0)

#define COMPUTE(B)                                                                                \
    do {                                                                                          \
        i32x4 af[8], bf[4];                                                                       \
        _Pragma("unroll") for (int m = 0; m < 8; m++)                                             \
            af[m] = *(const i32x4*)&As[(B)][(wr * 128 + m * 16 + la) * 64 + ((hi ^ fR) * 16)];    \
        _Pragma("unroll") for (int n = 0; n < 4; n++)                                             \
            bf[n] = *(const i32x4*)&Bs[(B)][(wc * 64 + n * 16 + la) * 64 + ((hi ^ fR) * 16)];     \
        _Pragma("unroll") for (int m = 0; m < 8; m++)                                             \
            _Pragma("unroll") for (int n = 0; n < 4; n++)                                         \
                acc[m][n] = __builtin_amdgcn_mfma_i32_16x16x64_i8(af[m], bf[n], acc[m][n], 0, 0, 0); \
    } while (0)

    // prologue: tiles 0,1 in flight (8 loads/thread); wait tile 0 (leave 4)
    STAGE(0, 0);
    STAGE(1, 1);
    asm volatile("s_waitcnt vmcnt(4)" ::: "memory");
    __builtin_amdgcn_s_barrier();

#pragma unroll
    for (int t = 0; t < 32; ++t) {
        if (t < 30) STAGE((t + 2) & 3, t + 2);
        if (t == 16) {
            // fold x-half into h-half scale: acc = rint(r * acc)
#pragma unroll
            for (int m = 0; m < 8; m++)
#pragma unroll
                for (int n = 0; n < 4; n++)
#pragma unroll
                    for (int q = 0; q < 4; q++)
                        acc[m][n][q] = (int)rintf((float)acc[m][n][q] * r);
        }
        COMPUTE(t & 3);
        if (t < 30) { asm volatile("s_waitcnt vmcnt(4)" ::: "memory"); }
        else if (t == 30) { asm volatile("s_waitcnt vmcnt(0)" ::: "memory"); }
        if (t < 31) __builtin_amdgcn_s_barrier();
    }

#undef STAGE
#undef COMPUTE

    // ---- epilogue: reconstruct gates from integer sums, LSTM pointwise ----
    float mna = params[0], mnh = params[2], mni = params[4], mnw = params[6];
    float za = mna + 128.0f * sa, zi = mni + 128.0f * si;
    float zh = mnh + 128.0f * sh, zw = mnw + 128.0f * sw;
    float C0 = 1024.0f * (za * zi + zh * zw);
    float cax = sa * zi, cah = sh * zw;
    float cbx = si * za, cbh = sw * zh;

    const int nb = bn + wc * 64;
    float colt[4];
#pragma unroll
    for (int g = 0; g < 4; ++g) {
        int np = nb + g * 16 + la;
        colt[g] = bc[np] + cbx * Rbi[np] + cbh * Rbh[np] + C0;
    }
    const int ub = (nb >> 6) * 16 + la;   // hidden-unit index

#pragma unroll
    for (int m = 0; m < 8; m++) {
#pragma unroll
        for (int q = 0; q < 4; q++) {
            int row = bm + wr * 128 + m * 16 + 4 * hi + q;
            float rterm = cax * Rax[row] + cah * Rah[row];
            float g0 = colt[0] + rterm + csh * (float)acc[m][0][q];
            float g1 = colt[1] + rterm + csh * (float)acc[m][1][q];
            float g2 = colt[2] + rterm + csh * (float)acc[m][2][q];
            float g3 = colt[3] + rterm + csh * (float)acc[m][3][q];
            float iv = 1.0f / (1.0f + __expf(-g0));
            float fv = 1.0f / (1.0f + __expf(-g1));
            float gv = tanhf(g2);
            float ov = 1.0f / (1.0f + __expf(-g3));
            size_t off = (size_t)row * 1024 + ub;
            float cv = c_in[off];
            float cn = fv * cv + iv * gv;
            float hn = ov * tanhf(cn);
            out[off] = hn;
            out[(size_t)8192 * 1024 + off] = cn;
        }
    }
}

extern "C" void kernel_launch(void* const* d_in, const int* in_sizes, int n_in,
                              void* d_out, int out_size, void* d_ws, size_t ws_size,
                              hipStream_t stream) {
    const float* x = (const float*)d_in[0];
    const float* h = (const float*)d_in[1];
    const float* c = (const float*)d_in[2];
    const float* wi = (const float*)d_in[3];
    const float* bi = (const float*)d_in[4];
    const float* wh = (const float*)d_in[5];
    const float* bh = (const float*)d_in[6];
    const int* nbits = (const int*)d_in[7];
    float* out = (float*)d_out;

    char* ws = (char*)d_ws;
    float* params   = (float*)ws;                   // 8 f32
    float* partials = (float*)(ws + 64);            // 4*256*2 f32
    float* bc  = (float*)(ws + 16384);              // 4096 f32
    float* Rax = (float*)(ws + 32768);              // 8192 f32
    float* Rah = (float*)(ws + 65536);              // 8192 f32
    float* Rbi = (float*)(ws + 98304);              // 4096 f32
    float* Rbh = (float*)(ws + 114688);             // 4096 f32
    s8* A8 = (s8*)(ws + 131072);                    // 8192*2048 i8 = 16MB
    s8* W8 = (s8*)(ws + 131072 + (size_t)16 * 1024 * 1024);  // 4096*2048 i8 = 8MB

    k_minmax_partial<<<dim3(NB_RED, 4), 256, 0, stream>>>(x, h, wi, wh, partials);
    k_minmax_final<<<4, 256, 0, stream>>>(partials, nbits, params);
    k_quant<<<24592, 256, 0, stream>>>(x, h, wi, wh, params, bi, bh,
                                       A8, W8, Rax, Rah, Rbi, Rbh, bc);
    k_gemm_lstm<<<512, 512, 0, stream>>>(A8, W8, params, bc, Rax, Rah, Rbi, Rbh, c, out);
}